// Round 9
// baseline (536.724 us; speedup 1.0000x reference)
//
#include <hip/hip_runtime.h>
#include <hip/hip_bf16.h>
#include <stdint.h>

typedef unsigned int u32;
typedef unsigned long long u64;
typedef unsigned char u8;
typedef unsigned short u16;

// ---------------------------------------------------------------------------
// Reduction order for n[v] = sum_f image[v,f]^2 bit-matches the XLA:CPU
// reference (H1 tree; vectorized form verified bit-exact, PASS R8).
// ---------------------------------------------------------------------------

// ---- K1: per-vertex squared norm (2 lanes/vertex, float4 loads) ----
__global__ __launch_bounds__(256) void vnorm_kernel(const float* __restrict__ image,
                                                    float* __restrict__ nrm, int V) {
#pragma clang fp contract(off)
  int t = blockIdx.x * 256 + threadIdx.x;
  int v = t >> 1, h = t & 1;
  if (v >= V) return;
  const float4* r4 = (const float4*)(image + (size_t)v * 128) + h;
  float4 a, x;
  x = r4[0];
  a.x = x.x * x.x; a.y = x.y * x.y; a.z = x.z * x.z; a.w = x.w * x.w;
#pragma unroll
  for (int i = 1; i < 16; ++i) {
    x = r4[i * 2];
    a.x = a.x + x.x * x.x; a.y = a.y + x.y * x.y;
    a.z = a.z + x.z * x.z; a.w = a.w + x.w * x.w;
  }
  float bx = __shfl_xor(a.x, 1), by = __shfl_xor(a.y, 1);
  float bz = __shfl_xor(a.z, 1), bw = __shfl_xor(a.w, 1);
  a.x = a.x + bx; a.y = a.y + by; a.z = a.z + bz; a.w = a.w + bw;
  float r0 = a.x + a.z;
  float r1 = a.y + a.w;
  float s = r0 + r1;
  if (h == 0) nrm[v] = s;
}

// ---- K2: per-edge priority, key, boundary + global min/max ----
__global__ __launch_bounds__(256) void edge_kernel(const float* __restrict__ nrm,
                                                   const float* __restrict__ vs,
                                                   const int* __restrict__ edges,
                                                   u64* __restrict__ keysA,
                                                   u8* __restrict__ bnd,
                                                   float* __restrict__ out_sq,
                                                   u32* __restrict__ gmm, int E) {
#pragma clang fp contract(off)
  __shared__ u32 smn[4], smx[4];
  int tid = threadIdx.x;
  int e = blockIdx.x * 256 + tid;
  u32 mn = 0xFFFFFFFFu, mx = 0u;
  if (e < E) {
    int v0 = edges[e], v1 = edges[E + e];
    float sq = nrm[v0] + nrm[v1];
    out_sq[e] = sq;
    u32 sb = __float_as_uint(sq);
    keysA[e] = ((u64)sb << 32) | (u32)e;
    float ax = vs[2 * v0], ay = vs[2 * v0 + 1];
    float bx = vs[2 * v1], by = vs[2 * v1 + 1];
    const float lo = 0.01f, hi = 0.99f;
    bool b = (ax < lo) | (ax > hi) | (ay < lo) | (ay > hi)
           | (bx < lo) | (bx > hi) | (by < lo) | (by > hi);
    bnd[e] = b ? 1 : 0;
    mn = sb; mx = sb;
  }
  int lane = tid & 63, wv = tid >> 6;
#pragma unroll
  for (int d = 32; d >= 1; d >>= 1) {
    u32 a = __shfl_xor(mn, d); mn = (a < mn) ? a : mn;
    u32 b2 = __shfl_xor(mx, d); mx = (b2 > mx) ? b2 : mx;
  }
  if (lane == 0) { smn[wv] = mn; smx[wv] = mx; }
  __syncthreads();
  if (tid == 0) {
    u32 m = smn[0], M = smx[0];
#pragma unroll
    for (int w = 1; w < 4; ++w) {
      if (smn[w] < m) m = smn[w];
      if (smx[w] > M) M = smx[w];
    }
    atomicMin(&gmm[0], m);
    atomicMax(&gmm[1], M);
  }
}

__device__ inline u32 bucket_of(u32 sb, u32 minv, u32 range) {
  return (u32)(((u64)(sb - minv) << 14) / ((u64)range + 1ull));   // 16384 buckets
}

// ---- K3: bucket histogram ----
__global__ __launch_bounds__(256) void hist_kernel(const u64* __restrict__ keysA,
                                                   const u32* __restrict__ gmm,
                                                   u32* __restrict__ ghist, int E) {
  int e = blockIdx.x * 256 + threadIdx.x;
  if (e >= E) return;
  u32 minv = gmm[0], range = gmm[1] - minv;
  u32 b = bucket_of((u32)(keysA[e] >> 32), minv, range);
  atomicAdd(&ghist[b], 1u);
}

// ---- K4: scan of 16384 bucket counts ----
__global__ __launch_bounds__(1024) void scan16k_kernel(const u32* __restrict__ ghist,
                                                       u32* __restrict__ starts,
                                                       u32* __restrict__ cursor, int E) {
  __shared__ u32 wsum[16];
  int tid = threadIdx.x;
  int lane = tid & 63, wv = tid >> 6;
  u32 loc[16];
  u32 s = 0;
#pragma unroll
  for (int i = 0; i < 16; ++i) { loc[i] = ghist[tid * 16 + i]; s += loc[i]; }
  u32 inc = s;
#pragma unroll
  for (int d = 1; d < 64; d <<= 1) {
    u32 t = __shfl_up(inc, d);
    if (lane >= d) inc += t;
  }
  if (lane == 63) wsum[wv] = inc;
  __syncthreads();
  if (tid == 0) {
    u32 r = 0;
#pragma unroll
    for (int w = 0; w < 16; ++w) { u32 t = wsum[w]; wsum[w] = r; r += t; }
  }
  __syncthreads();
  u32 run = wsum[wv] + (inc - s);
#pragma unroll
  for (int i = 0; i < 16; ++i) {
    starts[tid * 16 + i] = run;
    cursor[tid * 16 + i] = run;
    run += loc[i];
  }
  if (tid == 0) starts[16384] = (u32)E;
}

// ---- K5: scatter keys into bucket slots ----
__global__ __launch_bounds__(256) void scatter_kernel(const u64* __restrict__ keysA,
                                                      const u32* __restrict__ gmm,
                                                      u32* __restrict__ cursor,
                                                      u64* __restrict__ keysB, int E) {
  int e = blockIdx.x * 256 + threadIdx.x;
  if (e >= E) return;
  u64 key = keysA[e];
  u32 minv = gmm[0], range = gmm[1] - minv;
  u32 b = bucket_of((u32)(key >> 32), minv, range);
  u32 pos = atomicAdd(&cursor[b], 1u);
  keysB[pos] = key;
}

// ---- K6: per-bucket 128-elem bitonic sort (1 wave/bucket) + pack write ----
__global__ __launch_bounds__(256) void bucketsort_kernel(const u64* __restrict__ keysB,
                                                         const u32* __restrict__ starts,
                                                         const int* __restrict__ edges,
                                                         const u8* __restrict__ bnd,
                                                         u64* __restrict__ pack,
                                                         int E, int V, int Npad) {
  int tid = threadIdx.x;
  int lane = tid & 63;
  int w = blockIdx.x * 4 + (tid >> 6);           // bucket id
  u32 start = starts[w];
  int cnt = (int)(starts[w + 1] - start);
  if (cnt > 128) cnt = 128;                      // safety clamp (P ~ 0)
  u64 k0 = (lane < cnt) ? keysB[start + lane] : ~0ull;
  u64 k1 = (64 + lane < cnt) ? keysB[start + 64 + lane] : ~0ull;
  int idx0 = lane * 2, idx1 = lane * 2 + 1;
#pragma unroll
  for (int k = 2; k <= 128; k <<= 1) {
#pragma unroll
    for (int j = 64; j >= 1; j >>= 1) {
      if (j > k / 2) continue;
      if (j >= 2) {
        int lj = j >> 1;
        u64 p0 = __shfl_xor(k0, lj);
        u64 p1 = __shfl_xor(k1, lj);
        bool keepMin0 = (((idx0 & j) == 0) == ((idx0 & k) == 0));
        k0 = keepMin0 ? (k0 < p0 ? k0 : p0) : (k0 > p0 ? k0 : p0);
        k1 = keepMin0 ? (k1 < p1 ? k1 : p1) : (k1 > p1 ? k1 : p1);
      } else {
        bool up = ((idx0 & k) == 0);
        u64 mn = (k0 < k1) ? k0 : k1;
        u64 mx = (k0 < k1) ? k1 : k0;
        k0 = up ? mn : mx;
        k1 = up ? mx : mn;
      }
    }
  }
  if (idx0 < cnt) {
    u32 id = (u32)k0;
    int vv0 = edges[id], vv1 = edges[E + id];
    pack[start + idx0] = (u64)(u32)(vv0 | (vv1 << 16)) | ((u64)bnd[id] << 32);
  }
  if (idx1 < cnt) {
    u32 id = (u32)k1;
    int vv0 = edges[id], vv1 = edges[E + id];
    pack[start + idx1] = (u64)(u32)(vv0 | (vv1 << 16)) | ((u64)bnd[id] << 32);
  }
  // sentinel tail [E, Npad): unique dead verts per aligned 256-window
  int g = blockIdx.x * 256 + tid;
  int i = E + g;
  if (i < Npad) {
    u32 sv0 = (u32)V + (((u32)i & 255u) << 1);
    pack[i] = (u64)(sv0 | ((sv0 + 1) << 16)) | (1ull << 32);
  }
}

// ---- K7: per-256-edge-chunk intra shared-vertex flags (tag + closure) ----
__global__ __launch_bounds__(64) void flag_kernel(u64* __restrict__ pack, int nch) {
  __shared__ u16 tag[51072];
  int lane = threadIdx.x;
  size_t base = (size_t)blockIdx.x * 256;
  u64 p0 = pack[base + lane];
  u64 p1 = pack[base + 64 + lane];
  u64 p2 = pack[base + 128 + lane];
  u64 p3 = pack[base + 192 + lane];
#define FDEC(S) int fv0##S = (int)(p##S & 0xffff), fv1##S = (int)((p##S >> 16) & 0xffff); \
                u16 fid##S = (u16)(S * 64 + lane);
  FDEC(0) FDEC(1) FDEC(2) FDEC(3)
#define FWR(S) tag[fv0##S] = fid##S; tag[fv1##S] = fid##S;
  FWR(0) FWR(1) FWR(2) FWR(3)
  asm volatile("" ::: "memory");
#define FRD(S) int fm##S = ((int)tag[fv0##S] != (int)fid##S) | ((int)tag[fv1##S] != (int)fid##S);
  FRD(0) FRD(1) FRD(2) FRD(3)
  u64 any = __ballot(fm0 | fm1 | fm2 | fm3);
  if (any) {
#define FWR2(S) if (fm##S) { tag[fv0##S] = fid##S; tag[fv1##S] = fid##S; }
    FWR2(0) FWR2(1) FWR2(2) FWR2(3)
    asm volatile("" ::: "memory");
#define FRD2(S) fm##S |= ((int)tag[fv0##S] != (int)fid##S) | ((int)tag[fv1##S] != (int)fid##S);
    FRD2(0) FRD2(1) FRD2(2) FRD2(3)
  }
#define FOUT(S) pack[base + S * 64 + lane] = p##S | ((u64)(fm##S & 1) << 33);
  FOUT(0) FOUT(1) FOUT(2) FOUT(3)
}

// ---- K8: serial greedy collapse, 1 wave, 256 edges/chunk (4 slots/lane) ----
#define DEC4(S, PK) \
  int v0##S = (int)((PK) & 0xffff), v1##S = (int)(((PK) >> 16) & 0xffff);     \
  int nb##S = (int)(((PK) >> 32) & 1), fl##S = (int)(((PK) >> 33) & 1);       \
  int m0##S = (int)((wa##S >> (v0##S & 31)) & 1);                             \
  int m1##S = (int)((wb##S >> (v1##S & 31)) & 1);                             \
  int ca##S = m0##S & m1##S & (nb##S ^ 1);

#define U1(u) aa##u &= 1 ^ (d & (v0##u == kv)); ab##u &= 1 ^ (d & (v1##u == kv));

#define SER4(S, UPDLIST) { u64 t = __ballot(fl##S);                           \
    while (t) { int j = (int)__builtin_ctzll(t); t &= t - 1;                  \
      int cc = aa##S & ab##S & (nb##S ^ 1);                                   \
      int d = __builtin_amdgcn_readlane(cc, j);                               \
      int kv = __builtin_amdgcn_readlane(v1##S, j);                           \
      K += d; UPDLIST                                                         \
      sdo##S = (lane == j) ? d : sdo##S; } }

// threshold-sensitive chunk: exact per-slot resolution (runs at most once)
#define FBT(S) if (!done) {                                                   \
    asm volatile("" ::: "memory");                                            \
    u32 q0 = bits[v0##S >> 5], q1 = bits[v1##S >> 5];                         \
    int mm0 = (int)((q0 >> (v0##S & 31)) & 1);                                \
    int mm1 = (int)((q1 >> (v1##S & 31)) & 1);                                \
    int cd = mm0 & mm1 & (nb##S ^ 1);                                         \
    int pdd = cd & (fl##S ^ 1);                                               \
    int Ks = (int)__popcll(__ballot(pdd));                                    \
    int b0 = mm0, b1 = mm1, sd = 0;                                           \
    u64 t = __ballot(fl##S);                                                  \
    while (t) { int j = (int)__builtin_ctzll(t); t &= t - 1;                  \
      int cc = b0 & b1 & (nb##S ^ 1);                                         \
      int d = __builtin_amdgcn_readlane(cc, j);                               \
      int kv = __builtin_amdgcn_readlane(v1##S, j);                           \
      Ks += d;                                                                \
      b0 &= 1 ^ (d & (v0##S == kv)); b1 &= 1 ^ (d & (v1##S == kv));           \
      sd = (lane == j) ? d : sd; }                                            \
    int dd = fl##S ? sd : pdd;                                                \
    if (cnt - Ks >= target) {                                                 \
      if (dd) atomicAnd(&bits[v1##S >> 5], ~(1u << (v1##S & 31)));            \
      cnt -= Ks;                                                              \
      if (cnt <= target) done = 1;                                            \
    } else {                                                                  \
      int e0 = mm0, e1 = mm1, md = 0;                                         \
      for (int j = 0; j < 64; ++j) {                                          \
        int cc = (cnt > target) & e0 & e1 & (nb##S ^ 1);                      \
        int d = __builtin_amdgcn_readlane(cc, j);                             \
        int kv = __builtin_amdgcn_readlane(v1##S, j);                         \
        cnt -= d;                                                             \
        e0 &= 1 ^ (d & (v0##S == kv)); e1 &= 1 ^ (d & (v1##S == kv));         \
        md = (lane == j) ? d : md; }                                          \
      if (md) atomicAnd(&bits[v1##S >> 5], ~(1u << (v1##S & 31)));            \
      done = 1;                                                               \
    } }

#define STAGE4(P0, P1, P2, P3, N0, N1, N2, N3)                                \
  do {                                                                        \
    if (done) break;                                                          \
    DEC4(0, P0) DEC4(1, P1) DEC4(2, P2) DEC4(3, P3)                           \
    int kd0, kd1, kd2, kd3;                                                   \
    int K = 0;                                                                \
    u64 FB_ = __ballot(fl0 | fl1 | fl2 | fl3);                                \
    if (FB_ == 0) {                                                           \
      kd0 = ca0; kd1 = ca1; kd2 = ca2; kd3 = ca3;                             \
      K = (int)__popcll(__ballot(ca0)) + (int)__popcll(__ballot(ca1))         \
        + (int)__popcll(__ballot(ca2)) + (int)__popcll(__ballot(ca3));        \
    } else {                                                                  \
      int aa0 = m00, ab0 = m10, aa1 = m01, ab1 = m11;                         \
      int aa2 = m02, ab2 = m12, aa3 = m03, ab3 = m13;                         \
      int sdo0 = 0, sdo1 = 0, sdo2 = 0, sdo3 = 0;                             \
      int pd0 = ca0 & (fl0 ^ 1), pd1 = ca1 & (fl1 ^ 1);                       \
      int pd2 = ca2 & (fl2 ^ 1), pd3 = ca3 & (fl3 ^ 1);                       \
      K = (int)__popcll(__ballot(pd0)) + (int)__popcll(__ballot(pd1))         \
        + (int)__popcll(__ballot(pd2)) + (int)__popcll(__ballot(pd3));        \
      SER4(0, U1(0) U1(1) U1(2) U1(3))                                        \
      SER4(1, U1(1) U1(2) U1(3))                                              \
      SER4(2, U1(2) U1(3))                                                    \
      SER4(3, U1(3))                                                          \
      kd0 = fl0 ? sdo0 : pd0; kd1 = fl1 ? sdo1 : pd1;                         \
      kd2 = fl2 ? sdo2 : pd2; kd3 = fl3 ? sdo3 : pd3;                         \
    }                                                                         \
    if (cnt - K >= target) {                                                  \
      cnt -= K;                                                               \
      if (kd0) atomicAnd(&bits[v10 >> 5], ~(1u << (v10 & 31)));               \
      if (kd1) atomicAnd(&bits[v11 >> 5], ~(1u << (v11 & 31)));               \
      if (kd2) atomicAnd(&bits[v12 >> 5], ~(1u << (v12 & 31)));               \
      if (kd3) atomicAnd(&bits[v13 >> 5], ~(1u << (v13 & 31)));               \
      asm volatile("" ::: "memory");                                          \
      if (cnt <= target) { done = 1; }                                        \
      else {                                                                  \
        int x0, x1;                                                           \
        x0 = (int)((N0) & 0xffff); x1 = (int)(((N0) >> 16) & 0xffff);         \
        wa0 = bits[x0 >> 5]; wb0 = bits[x1 >> 5];                             \
        x0 = (int)((N1) & 0xffff); x1 = (int)(((N1) >> 16) & 0xffff);         \
        wa1 = bits[x0 >> 5]; wb1 = bits[x1 >> 5];                             \
        x0 = (int)((N2) & 0xffff); x1 = (int)(((N2) >> 16) & 0xffff);         \
        wa2 = bits[x0 >> 5]; wb2 = bits[x1 >> 5];                             \
        x0 = (int)((N3) & 0xffff); x1 = (int)(((N3) >> 16) & 0xffff);         \
        wa3 = bits[x0 >> 5]; wb3 = bits[x1 >> 5];                             \
      }                                                                       \
    } else {                                                                  \
      FBT(0) FBT(1) FBT(2) FBT(3)                                             \
      if (!done) {                                                            \
        asm volatile("" ::: "memory");                                        \
        int x0, x1;                                                           \
        x0 = (int)((N0) & 0xffff); x1 = (int)(((N0) >> 16) & 0xffff);         \
        wa0 = bits[x0 >> 5]; wb0 = bits[x1 >> 5];                             \
        x0 = (int)((N1) & 0xffff); x1 = (int)(((N1) >> 16) & 0xffff);         \
        wa1 = bits[x0 >> 5]; wb1 = bits[x1 >> 5];                             \
        x0 = (int)((N2) & 0xffff); x1 = (int)(((N2) >> 16) & 0xffff);         \
        wa2 = bits[x0 >> 5]; wb2 = bits[x1 >> 5];                             \
        x0 = (int)((N3) & 0xffff); x1 = (int)(((N3) >> 16) & 0xffff);         \
        wa3 = bits[x0 >> 5]; wb3 = bits[x1 >> 5];                             \
      }                                                                       \
    }                                                                         \
  } while (0)

__global__ __launch_bounds__(64) void collapse_kernel(const u64* __restrict__ pack,
                                                      const int* __restrict__ tgt,
                                                      float* __restrict__ out,
                                                      u32* __restrict__ gbits,
                                                      int V, int E, int nsc) {
  __shared__ u32 bits[1600];
  int lane = threadIdx.x;
  for (int i = lane; i < 1600; i += 64) bits[i] = 0xFFFFFFFFu;
  int target = tgt[0];
  int cnt = V;
  int done = 0;
  const u64* p = pack;
  u64 c0  = p[lane +   0], c1  = p[lane +  64], c2  = p[lane + 128], c3  = p[lane + 192];
  u64 c4  = p[lane + 256], c5  = p[lane + 320], c6  = p[lane + 384], c7  = p[lane + 448];
  u64 c8  = p[lane + 512], c9  = p[lane + 576], c10 = p[lane + 640], c11 = p[lane + 704];
  u64 c12 = p[lane + 768], c13 = p[lane + 832], c14 = p[lane + 896], c15 = p[lane + 960];
  u32 wa0, wb0, wa1, wb1, wa2, wb2, wa3, wb3;
  asm volatile("" ::: "memory");   // keep initial reads after bits init
  {
    int x0, x1;
    x0 = (int)(c0 & 0xffff); x1 = (int)((c0 >> 16) & 0xffff);
    wa0 = bits[x0 >> 5]; wb0 = bits[x1 >> 5];
    x0 = (int)(c1 & 0xffff); x1 = (int)((c1 >> 16) & 0xffff);
    wa1 = bits[x0 >> 5]; wb1 = bits[x1 >> 5];
    x0 = (int)(c2 & 0xffff); x1 = (int)((c2 >> 16) & 0xffff);
    wa2 = bits[x0 >> 5]; wb2 = bits[x1 >> 5];
    x0 = (int)(c3 & 0xffff); x1 = (int)((c3 >> 16) & 0xffff);
    wa3 = bits[x0 >> 5]; wb3 = bits[x1 >> 5];
  }
  for (int s = 0; s < nsc; ++s) {
    const u64* np = pack + (size_t)((s + 1 < nsc) ? (s + 1) : s) * 1024;
    u64 n0  = np[lane +   0], n1  = np[lane +  64], n2  = np[lane + 128], n3  = np[lane + 192];
    u64 n4  = np[lane + 256], n5  = np[lane + 320], n6  = np[lane + 384], n7  = np[lane + 448];
    u64 n8  = np[lane + 512], n9  = np[lane + 576], n10 = np[lane + 640], n11 = np[lane + 704];
    u64 n12 = np[lane + 768], n13 = np[lane + 832], n14 = np[lane + 896], n15 = np[lane + 960];
    STAGE4(c0,  c1,  c2,  c3,   c4,  c5,  c6,  c7);
    STAGE4(c4,  c5,  c6,  c7,   c8,  c9,  c10, c11);
    STAGE4(c8,  c9,  c10, c11,  c12, c13, c14, c15);
    STAGE4(c12, c13, c14, c15,  n0,  n1,  n2,  n3);
    c0 = n0;  c1 = n1;  c2 = n2;  c3 = n3;
    c4 = n4;  c5 = n5;  c6 = n6;  c7 = n7;
    c8 = n8;  c9 = n9;  c10 = n10; c11 = n11;
    c12 = n12; c13 = n13; c14 = n14; c15 = n15;
    if (done) break;
  }
  asm volatile("" ::: "memory");
  for (int i = lane; i < 1600; i += 64) gbits[i] = bits[i];
  if (lane == 0) out[E + V] = (float)cnt;
}

// ---- K9: expand bit-mask to float outputs ----
__global__ __launch_bounds__(256) void expand_kernel(const u32* __restrict__ gbits,
                                                     float* __restrict__ out,
                                                     int V, int E) {
  int i = blockIdx.x * 256 + threadIdx.x;
  if (i < V) out[E + i] = ((gbits[i >> 5] >> (i & 31)) & 1) ? 1.0f : 0.0f;
}

extern "C" void kernel_launch(void* const* d_in, const int* in_sizes, int n_in,
                              void* d_out, int out_size, void* d_ws, size_t ws_size,
                              hipStream_t stream) {
  const float* image = (const float*)d_in[0];
  const float* vs    = (const float*)d_in[1];
  const int*   edges = (const int*)d_in[2];
  const int*   tgt   = (const int*)d_in[3];
  int V = in_sizes[1] / 2;                 // 50000
  int E = in_sizes[2] / 2;                 // 150000
  int Npad = ((E + 1023) / 1024) * 1024;   // 150528
  int nch = Npad / 256;                    // 588 flag chunks
  int nsc = Npad / 1024;                   // 147 collapse superchunks

  char* ws = (char*)d_ws;
  size_t o = 0;
  u64* keysA  = (u64*)(ws + o); o += (size_t)E * 8;
  u64* keysB  = (u64*)(ws + o); o += (size_t)E * 8;
  u64* pack   = (u64*)(ws + o); o += (size_t)Npad * 8;
  float* nrm  = (float*)(ws + o); o += (size_t)V * 4;
  u8*  bnd    = (u8*)(ws + o);  o += (size_t)E;
  o = (o + 255) & ~(size_t)255;
  u32* ghist  = (u32*)(ws + o); o += 16384 * 4;
  u32* starts = (u32*)(ws + o); o += 16385 * 4;
  u32* cursor = (u32*)(ws + o); o += 16384 * 4;
  u32* gbits  = (u32*)(ws + o); o += 6400;
  u32* gmm    = (u32*)(ws + o); o += 256;
  float* out = (float*)d_out;

  (void)hipMemsetAsync(ghist, 0, 16384 * 4, stream);
  (void)hipMemsetAsync(&gmm[0], 0xFF, 4, stream);   // min = 0xFFFFFFFF
  (void)hipMemsetAsync(&gmm[1], 0x00, 4, stream);   // max = 0

  int eb = (E + 255) / 256;
  vnorm_kernel<<<dim3((2 * V + 255) / 256), dim3(256), 0, stream>>>(image, nrm, V);
  edge_kernel<<<dim3(eb), dim3(256), 0, stream>>>(nrm, vs, edges, keysA, bnd, out, gmm, E);
  hist_kernel<<<dim3(eb), dim3(256), 0, stream>>>(keysA, gmm, ghist, E);
  scan16k_kernel<<<dim3(1), dim3(1024), 0, stream>>>(ghist, starts, cursor, E);
  scatter_kernel<<<dim3(eb), dim3(256), 0, stream>>>(keysA, gmm, cursor, keysB, E);
  bucketsort_kernel<<<dim3(4096), dim3(256), 0, stream>>>(keysB, starts, edges, bnd,
                                                          pack, E, V, Npad);
  flag_kernel<<<dim3(nch), dim3(64), 0, stream>>>(pack, nch);
  collapse_kernel<<<dim3(1), dim3(64), 0, stream>>>(pack, tgt, out, gbits, V, E, nsc);
  expand_kernel<<<dim3((V + 255) / 256), dim3(256), 0, stream>>>(gbits, out, V, E);
}